// Round 1
// baseline (219.261 us; speedup 1.0000x reference)
//
#include <hip/hip_runtime.h>
#include <hip/hip_bf16.h>

typedef __bf16 bf16x8 __attribute__((ext_vector_type(8)));
typedef float  f32x4  __attribute__((ext_vector_type(4)));

#define HF 128          // hidden dim
#define W1K 256         // W1 inner dim (2H)

// Block = 256 threads (4 waves). Each wave handles 64 edges per tile-iter.
// LDS holds W1 as bf16 in MFMA-B fragment order: [pair p=n*8+kk][lane][8].
__global__ __launch_bounds__(256, 2) void edge_mlp_kernel(
    const float* __restrict__ x_src, const float* __restrict__ x_dst,
    const int*   __restrict__ src_idx, const int* __restrict__ dst_idx,
    const float* __restrict__ W1, const float* __restrict__ b1,
    const float* __restrict__ W2, const float* __restrict__ b2,
    float* __restrict__ out, int nEdges)
{
    __shared__ __align__(16) __bf16 w1lds[64 * 64 * 8];   // 64 KiB

    const int tid  = threadIdx.x;
    const int lane = tid & 63;
    const int wid  = tid >> 6;      // wave 0..3
    const int l15  = lane & 15;     // edge-slot (A) / channel (B,C)
    const int lg   = lane >> 4;     // k-group / edge-row-group

    // ---- stage W1: fp32 global -> bf16 LDS, fragment-ordered ----
    // pair p: n = p>>3 (N-tile), kk = p&7 (K-step)
    for (int p = wid; p < 64; p += 4) {
        const int n   = p >> 3;
        const int kk  = p & 7;
        const int row = n * 16 + l15;        // output channel
        const int col = kk * 32 + lg * 8;    // k
        const float* src = W1 + row * W1K + col;
        bf16x8 v;
        #pragma unroll
        for (int i = 0; i < 8; ++i) v[i] = (__bf16)src[i];
        *reinterpret_cast<bf16x8*>(&w1lds[(p * 64 + lane) * 8]) = v;
    }
    __syncthreads();

    // per-lane layer-2 constants (channel = n*16 + l15), hoisted
    float w2v[8], b1v[8];
    #pragma unroll
    for (int n = 0; n < 8; ++n) {
        w2v[n] = W2[n * 16 + l15];
        b1v[n] = b1[n * 16 + l15];
    }
    const float b2v = b2[0];

    const int ntiles = nEdges / 256;   // 640000/256 = 2500, exact
    for (int t = blockIdx.x; t < ntiles; t += gridDim.x) {
        const int ebase = t * 256 + wid * 64;

        const float* srow[4];
        const float* drow[4];
        #pragma unroll
        for (int m = 0; m < 4; ++m) {
            const int e  = ebase + m * 16 + l15;
            const int si = src_idx[e];
            const int di = dst_idx[e];
            srow[m] = x_src + (size_t)si * HF + lg * 8;
            drow[m] = x_dst + (size_t)di * HF + lg * 8;
        }

        f32x4 acc[4][8];
        #pragma unroll
        for (int m = 0; m < 4; ++m)
            #pragma unroll
            for (int n = 0; n < 8; ++n)
                acc[m][n] = (f32x4){0.f, 0.f, 0.f, 0.f};

        #pragma unroll
        for (int kk = 0; kk < 8; ++kk) {
            bf16x8 a[4];
            #pragma unroll
            for (int m = 0; m < 4; ++m) {
                const float* p = (kk < 4) ? (srow[m] + kk * 32)
                                          : (drow[m] + (kk - 4) * 32);
                f32x4 u0 = *reinterpret_cast<const f32x4*>(p);
                f32x4 u1 = *reinterpret_cast<const f32x4*>(p + 4);
                bf16x8 av;
                #pragma unroll
                for (int i = 0; i < 4; ++i) {
                    av[i]     = (__bf16)u0[i];
                    av[i + 4] = (__bf16)u1[i];
                }
                a[m] = av;
            }
            #pragma unroll
            for (int n = 0; n < 8; ++n) {
                bf16x8 bfrag = *reinterpret_cast<const bf16x8*>(
                    &w1lds[((n * 8 + kk) * 64 + lane) * 8]);
                #pragma unroll
                for (int m = 0; m < 4; ++m) {
                    acc[m][n] = __builtin_amdgcn_mfma_f32_16x16x32_bf16(
                        a[m], bfrag, acc[m][n], 0, 0, 0);
                }
            }
        }

        // ---- epilogue: bias + relu + layer2 dot + lane reduce + store ----
        #pragma unroll
        for (int m = 0; m < 4; ++m) {
            float part[4];
            #pragma unroll
            for (int r = 0; r < 4; ++r) {
                float s = 0.f;
                #pragma unroll
                for (int n = 0; n < 8; ++n) {
                    float v = acc[m][n][r] + b1v[n];
                    v = fmaxf(v, 0.f);
                    s += v * w2v[n];
                }
                part[r] = s;
            }
            // sum across the 16 lanes (channel classes) within each lane-group
            #pragma unroll
            for (int off = 1; off < 16; off <<= 1) {
                #pragma unroll
                for (int r = 0; r < 4; ++r)
                    part[r] += __shfl_xor(part[r], off, 64);
            }
            if (l15 == m) {  // one lane per 16-lane group stores 4 edges
                f32x4 v4 = { part[0] + b2v, part[1] + b2v,
                             part[2] + b2v, part[3] + b2v };
                *reinterpret_cast<f32x4*>(&out[ebase + m * 16 + lg * 4]) = v4;
            }
        }
    }
}

extern "C" void kernel_launch(void* const* d_in, const int* in_sizes, int n_in,
                              void* d_out, int out_size, void* d_ws, size_t ws_size,
                              hipStream_t stream) {
    const float* x_src  = (const float*)d_in[0];
    const float* x_dst  = (const float*)d_in[1];
    const int*   sidx   = (const int*)d_in[2];
    const int*   didx   = (const int*)d_in[3];
    const float* W1     = (const float*)d_in[4];
    const float* b1     = (const float*)d_in[5];
    const float* W2     = (const float*)d_in[6];
    const float* b2     = (const float*)d_in[7];
    float* out = (float*)d_out;
    const int nEdges = in_sizes[2];

    edge_mlp_kernel<<<512, 256, 0, stream>>>(
        x_src, x_dst, sidx, didx, W1, b1, W2, b2, out, nEdges);
}

// Round 2
// 87.843 us; speedup vs baseline: 2.4960x; 2.4960x over previous
//
#include <hip/hip_runtime.h>
#include <hip/hip_bf16.h>

typedef __bf16 bf16x8 __attribute__((ext_vector_type(8)));
typedef float  f32x4  __attribute__((ext_vector_type(4)));

#define HF 128          // hidden dim
#define W1K 256         // W1 inner dim (2H)

// ================= Kernel 1: per-node linear precompute =================
// u[n][c] = sum_k W1[c,k]      * x_src[n,k]  + b1[c]   (A = W1[:, :128])
// v[n][c] = sum_k W1[c,128+k]  * x_dst[n,k]            (B = W1[:, 128:])
// stored bf16 row-major [node][128] in workspace.
__global__ __launch_bounds__(256, 2) void node_precompute_kernel(
    const float* __restrict__ x_src, const float* __restrict__ x_dst,
    const float* __restrict__ W1, const float* __restrict__ b1,
    __bf16* __restrict__ u, __bf16* __restrict__ v, int nNodes)
{
    __shared__ __align__(16) __bf16 wlds[32 * 64 * 8];   // 32 KiB

    const int which = blockIdx.y;                 // 0 -> u/A, 1 -> v/B
    const float* __restrict__ x = which ? x_dst : x_src;
    const float* __restrict__ W = W1 + (which ? HF : 0);
    __bf16* __restrict__ outp = which ? v : u;

    const int tid  = threadIdx.x;
    const int lane = tid & 63;
    const int wid  = tid >> 6;
    const int l15  = lane & 15;
    const int lg   = lane >> 4;

    // stage W (128x128 fp32, row stride 256) -> bf16 LDS, MFMA-B fragment order
    for (int p = wid; p < 32; p += 4) {
        const int n  = p >> 2;                    // N-tile (channel/16)
        const int kk = p & 3;                     // K-step
        const float* srcp = W + (n * 16 + l15) * W1K + kk * 32 + lg * 8;
        bf16x8 w8;
        #pragma unroll
        for (int i = 0; i < 8; ++i) w8[i] = (__bf16)srcp[i];
        *reinterpret_cast<bf16x8*>(&wlds[(p * 64 + lane) * 8]) = w8;
    }
    __syncthreads();

    const int rowbase = blockIdx.x * 256 + wid * 64;

    const float* rowp[4];
    #pragma unroll
    for (int m = 0; m < 4; ++m) {
        int row = rowbase + m * 16 + l15;
        row = min(row, nNodes - 1);               // clamp tail loads
        rowp[m] = x + (size_t)row * HF + lg * 8;
    }

    f32x4 acc[4][8];
    #pragma unroll
    for (int m = 0; m < 4; ++m)
        #pragma unroll
        for (int n = 0; n < 8; ++n)
            acc[m][n] = (f32x4){0.f, 0.f, 0.f, 0.f};

    #pragma unroll
    for (int kk = 0; kk < 4; ++kk) {
        bf16x8 a[4];
        #pragma unroll
        for (int m = 0; m < 4; ++m) {
            const float* p = rowp[m] + kk * 32;
            f32x4 u0 = *reinterpret_cast<const f32x4*>(p);
            f32x4 u1 = *reinterpret_cast<const f32x4*>(p + 4);
            bf16x8 av;
            #pragma unroll
            for (int i = 0; i < 4; ++i) {
                av[i]     = (__bf16)u0[i];
                av[i + 4] = (__bf16)u1[i];
            }
            a[m] = av;
        }
        #pragma unroll
        for (int n = 0; n < 8; ++n) {
            bf16x8 bfrag = *reinterpret_cast<const bf16x8*>(
                &wlds[((n * 4 + kk) * 64 + lane) * 8]);
            #pragma unroll
            for (int m = 0; m < 4; ++m) {
                acc[m][n] = __builtin_amdgcn_mfma_f32_16x16x32_bf16(
                    a[m], bfrag, acc[m][n], 0, 0, 0);
            }
        }
    }

    float b1v[8];
    #pragma unroll
    for (int n = 0; n < 8; ++n)
        b1v[n] = (which == 0) ? b1[n * 16 + l15] : 0.f;

    // C/D layout: channel = n*16 + l15, row-in-tile = lg*4 + r
    #pragma unroll
    for (int m = 0; m < 4; ++m) {
        #pragma unroll
        for (int r = 0; r < 4; ++r) {
            const int row = rowbase + m * 16 + lg * 4 + r;
            if (row < nNodes) {
                #pragma unroll
                for (int n = 0; n < 8; ++n)
                    outp[(size_t)row * HF + n * 16 + l15] =
                        (__bf16)(acc[m][n][r] + b1v[n]);
            }
        }
    }
}

// ================= Kernel 2: per-edge score (pure gather) =================
// score[e] = W2 . relu(u[src[e]] + v[dst[e]]) + b2
// 16 lanes per edge, 8 channels (16 B bf16) per lane, 2 edges per subgroup.
__global__ __launch_bounds__(256) void edge_score_kernel(
    const __bf16* __restrict__ u, const __bf16* __restrict__ v,
    const int* __restrict__ sidx, const int* __restrict__ didx,
    const float* __restrict__ W2, const float* __restrict__ b2,
    float* __restrict__ out, int nEdges)
{
    const int tid = threadIdx.x;
    const int sub = tid >> 4;        // 0..15
    const int l16 = tid & 15;

    const int e0 = blockIdx.x * 32 + sub;
    const int e1 = e0 + 16;
    const int c0 = min(e0, nEdges - 1);
    const int c1 = min(e1, nEdges - 1);

    float w2v[8];
    #pragma unroll
    for (int j = 0; j < 8; ++j) w2v[j] = W2[l16 * 8 + j];
    const float b2v = b2[0];

    const int si0 = sidx[c0], di0 = didx[c0];
    const int si1 = sidx[c1], di1 = didx[c1];

    const bf16x8 u0 = *reinterpret_cast<const bf16x8*>(u + (size_t)si0 * HF + l16 * 8);
    const bf16x8 v0 = *reinterpret_cast<const bf16x8*>(v + (size_t)di0 * HF + l16 * 8);
    const bf16x8 u1 = *reinterpret_cast<const bf16x8*>(u + (size_t)si1 * HF + l16 * 8);
    const bf16x8 v1 = *reinterpret_cast<const bf16x8*>(v + (size_t)di1 * HF + l16 * 8);

    float s0 = 0.f, s1 = 0.f;
    #pragma unroll
    for (int j = 0; j < 8; ++j) {
        s0 += fmaxf((float)u0[j] + (float)v0[j], 0.f) * w2v[j];
        s1 += fmaxf((float)u1[j] + (float)v1[j], 0.f) * w2v[j];
    }

    #pragma unroll
    for (int off = 1; off < 16; off <<= 1) {
        s0 += __shfl_xor(s0, off, 64);
        s1 += __shfl_xor(s1, off, 64);
    }

    if (l16 == 0) {
        if (e0 < nEdges) out[e0] = s0 + b2v;
        if (e1 < nEdges) out[e1] = s1 + b2v;
    }
}

// ================= Fallback: fused single kernel (round-1) =================
__global__ __launch_bounds__(256, 2) void edge_mlp_kernel(
    const float* __restrict__ x_src, const float* __restrict__ x_dst,
    const int*   __restrict__ src_idx, const int* __restrict__ dst_idx,
    const float* __restrict__ W1, const float* __restrict__ b1,
    const float* __restrict__ W2, const float* __restrict__ b2,
    float* __restrict__ out, int nEdges)
{
    __shared__ __align__(16) __bf16 w1lds[64 * 64 * 8];

    const int tid  = threadIdx.x;
    const int lane = tid & 63;
    const int wid  = tid >> 6;
    const int l15  = lane & 15;
    const int lg   = lane >> 4;

    for (int p = wid; p < 64; p += 4) {
        const int n   = p >> 3;
        const int kk  = p & 7;
        const float* src = W1 + (n * 16 + l15) * W1K + kk * 32 + lg * 8;
        bf16x8 w8;
        #pragma unroll
        for (int i = 0; i < 8; ++i) w8[i] = (__bf16)src[i];
        *reinterpret_cast<bf16x8*>(&w1lds[(p * 64 + lane) * 8]) = w8;
    }
    __syncthreads();

    float w2v[8], b1v[8];
    #pragma unroll
    for (int n = 0; n < 8; ++n) {
        w2v[n] = W2[n * 16 + l15];
        b1v[n] = b1[n * 16 + l15];
    }
    const float b2v = b2[0];

    const int ntiles = nEdges / 256;
    for (int t = blockIdx.x; t < ntiles; t += gridDim.x) {
        const int ebase = t * 256 + wid * 64;

        const float* srow[4];
        const float* drow[4];
        #pragma unroll
        for (int m = 0; m < 4; ++m) {
            const int e  = ebase + m * 16 + l15;
            srow[m] = x_src + (size_t)src_idx[e] * HF + lg * 8;
            drow[m] = x_dst + (size_t)dst_idx[e] * HF + lg * 8;
        }

        f32x4 acc[4][8];
        #pragma unroll
        for (int m = 0; m < 4; ++m)
            #pragma unroll
            for (int n = 0; n < 8; ++n)
                acc[m][n] = (f32x4){0.f, 0.f, 0.f, 0.f};

        #pragma unroll
        for (int kk = 0; kk < 8; ++kk) {
            bf16x8 a[4];
            #pragma unroll
            for (int m = 0; m < 4; ++m) {
                const float* p = (kk < 4) ? (srow[m] + kk * 32)
                                          : (drow[m] + (kk - 4) * 32);
                f32x4 u0 = *reinterpret_cast<const f32x4*>(p);
                f32x4 u1 = *reinterpret_cast<const f32x4*>(p + 4);
                bf16x8 av;
                #pragma unroll
                for (int i = 0; i < 4; ++i) {
                    av[i]     = (__bf16)u0[i];
                    av[i + 4] = (__bf16)u1[i];
                }
                a[m] = av;
            }
            #pragma unroll
            for (int n = 0; n < 8; ++n) {
                bf16x8 bfrag = *reinterpret_cast<const bf16x8*>(
                    &w1lds[((n * 8 + kk) * 64 + lane) * 8]);
                #pragma unroll
                for (int m = 0; m < 4; ++m) {
                    acc[m][n] = __builtin_amdgcn_mfma_f32_16x16x32_bf16(
                        a[m], bfrag, acc[m][n], 0, 0, 0);
                }
            }
        }

        #pragma unroll
        for (int m = 0; m < 4; ++m) {
            float part[4];
            #pragma unroll
            for (int r = 0; r < 4; ++r) {
                float s = 0.f;
                #pragma unroll
                for (int n = 0; n < 8; ++n) {
                    float hv = acc[m][n][r] + b1v[n];
                    s += fmaxf(hv, 0.f) * w2v[n];
                }
                part[r] = s;
            }
            #pragma unroll
            for (int off = 1; off < 16; off <<= 1) {
                #pragma unroll
                for (int r = 0; r < 4; ++r)
                    part[r] += __shfl_xor(part[r], off, 64);
            }
            if (l15 == m) {
                f32x4 v4 = { part[0] + b2v, part[1] + b2v,
                             part[2] + b2v, part[3] + b2v };
                *reinterpret_cast<f32x4*>(&out[ebase + m * 16 + lg * 4]) = v4;
            }
        }
    }
}

extern "C" void kernel_launch(void* const* d_in, const int* in_sizes, int n_in,
                              void* d_out, int out_size, void* d_ws, size_t ws_size,
                              hipStream_t stream) {
    const float* x_src  = (const float*)d_in[0];
    const float* x_dst  = (const float*)d_in[1];
    const int*   sidx   = (const int*)d_in[2];
    const int*   didx   = (const int*)d_in[3];
    const float* W1     = (const float*)d_in[4];
    const float* b1     = (const float*)d_in[5];
    const float* W2     = (const float*)d_in[6];
    const float* b2     = (const float*)d_in[7];
    float* out = (float*)d_out;

    const int nEdges = in_sizes[2];
    const int nNodes = in_sizes[0] / HF;

    const size_t needed = (size_t)2 * nNodes * HF * sizeof(__bf16);  // u + v
    if (ws_size >= needed) {
        __bf16* u = (__bf16*)d_ws;
        __bf16* v = u + (size_t)nNodes * HF;

        dim3 pgrid((nNodes + 255) / 256, 2);
        node_precompute_kernel<<<pgrid, 256, 0, stream>>>(
            x_src, x_dst, W1, b1, u, v, nNodes);

        const int egrid = (nEdges + 31) / 32;
        edge_score_kernel<<<egrid, 256, 0, stream>>>(
            u, v, sidx, didx, W2, b2, out, nEdges);
    } else {
        edge_mlp_kernel<<<512, 256, 0, stream>>>(
            x_src, x_dst, sidx, didx, W1, b1, W2, b2, out, nEdges);
    }
}